// Round 7
// baseline (11809.565 us; speedup 1.0000x reference)
//
#include <hip/hip_runtime.h>

// ConsMaxAttention MI355X — ROUND 7: fp32 OUTPUT (the round-6 discovery).
// Round-6 measurement: out[0]=8192 (u16) read back as ~0 => d_out is FLOAT32.
// ("bf16" in the harness label is hard-coded text; ref output dtype is fp32.)
// Retro-explains r1 (NaN: bf16-decoding fp32 inputs) and r2-r5 (u16 stores
// pair-packed into fp32 words: decorrelated, scale-preserved, half-buffer).
// This round = r4's validated naive structure with ONE change: fp32 stores.
// Inputs fp32 (proven r1/r2), positional slots (proven r3==r4).
// Math: probs = exp(scores - rowmax)/gamma (beta cancels in the max shift);
// W indexed [o,k] per reference einsum 'bsh,oh->bso' (torch Linear).
// ws: bf16 q/k/v per-head slices (768 KB) + bf16 ctx [B,S,HID] (8.4 MB).

typedef unsigned short u16;

constexpr int B_  = 2;
constexpr int S_  = 2048;
constexpr int HID = 1024;
constexpr int NH  = 16;
constexpr int HD  = 64;
constexpr int M_  = B_ * S_;   // 4096

__device__ __forceinline__ float us2f(u16 u) {
    union { unsigned int i; float f; } x;
    x.i = ((unsigned int)u) << 16;
    return x.f;
}
__device__ __forceinline__ u16 f2us(float f) {
    union { float f; unsigned int i; } x;
    x.f = f;
    unsigned int r = x.i + 0x7FFFu + ((x.i >> 16) & 1u);  // RNE
    return (u16)(r >> 16);
}

// Q/K/V projection for ONE (b,h): y[s,col] = hs[b,s,:]·W[col,:] + bias[col],
// col = h*64 + tid, W row-major [o,k]. 64 threads per block.
__global__ __launch_bounds__(64)
void qkv_head(const float* __restrict__ hs,
              const float* __restrict__ Wq, const float* __restrict__ bq,
              const float* __restrict__ Wk, const float* __restrict__ bk,
              const float* __restrict__ Wv, const float* __restrict__ bv,
              u16* __restrict__ qs, u16* __restrict__ ks, u16* __restrict__ vs,
              int b, int h)
{
    __shared__ float xs[HID];
    const int s   = blockIdx.x;
    const int wch = blockIdx.y;
    const int tid = threadIdx.x;

    const size_t mrow = (size_t)(b * S_ + s) * HID;
    for (int j = tid; j < HID; j += 64) xs[j] = hs[mrow + j];
    __syncthreads();

    const float* W  = (wch == 0) ? Wq : (wch == 1) ? Wk : Wv;
    const float* bi = (wch == 0) ? bq : (wch == 1) ? bk : bv;
    u16*         o  = (wch == 0) ? qs : (wch == 1) ? ks : vs;

    const int col = h * HD + tid;
    float acc = bi[col];
    const size_t wrow = (size_t)col * HID;       // W[o=col, k]
    for (int kk = 0; kk < HID; ++kk) acc += xs[kk] * W[wrow + kk];
    o[(size_t)s * HD + tid] = f2us(acc);
}

// Attention for ONE (b,h). q/k/v: [S,HD] bf16 slices. One wave per q-row.
// ctx (bf16, ws) gets ctx[b, s, h*64 + d].
__global__ __launch_bounds__(256)
void attn_head(const u16* __restrict__ q, const u16* __restrict__ k,
               const u16* __restrict__ v, const float* __restrict__ mask,
               const float* __restrict__ gamma, u16* __restrict__ ctx,
               int b, int h)
{
    __shared__ float sc[4][S_];   // 32 KB
    __shared__ float qb[4][HD];

    const int tid  = threadIdx.x;
    const int lane = tid & 63;
    const int w    = tid >> 6;
    const int qi   = blockIdx.x * 4 + w;

    qb[w][lane] = us2f(q[(size_t)qi * HD + lane]);
    __syncthreads();

    // phase 1: scores + per-lane max
    float mx = -1e30f;
    for (int t = lane; t < S_; t += 64) {
        const u16* Kp = k + (size_t)t * HD;
        float s = 0.0f;
        for (int d = 0; d < HD; ++d) s += qb[w][d] * us2f(Kp[d]);
        const float mv = mask[(size_t)b * S_ + t];
        s = s * 0.125f + (1.0f - mv) * (-10000.0f);
        sc[w][t] = s;
        mx = fmaxf(mx, s);
    }
    #pragma unroll
    for (int off = 1; off < 64; off <<= 1)
        mx = fmaxf(mx, __shfl_xor(mx, off, 64));
    __syncthreads();

    // phase 2: exp(s - rowmax) (each lane rewrites exactly what it wrote)
    for (int t = lane; t < S_; t += 64)
        sc[w][t] = __expf(sc[w][t] - mx);
    __syncthreads();

    // phase 3: o[d=lane] = sum_t p_t * V[t][d]
    float o = 0.0f;
    for (int t = 0; t < S_; ++t)
        o += sc[w][t] * us2f(v[(size_t)t * HD + lane]);

    ctx[(size_t)(b * S_ + qi) * HID + h * HD + lane] = f2us(o / gamma[0]);
}

// Final projection: out[m,n] = ctx[m,:]·Wo[n,:] + bo[n], FP32 stores.
__global__ __launch_bounds__(256)
void out_proj(const u16* __restrict__ ctx, const float* __restrict__ Wo,
              const float* __restrict__ bo, float* __restrict__ out)
{
    __shared__ float xs[HID];
    const int m   = blockIdx.x;
    const int tid = threadIdx.x;
    const size_t row = (size_t)m * HID;

    for (int j = tid; j < HID; j += 256) xs[j] = us2f(ctx[row + j]);
    __syncthreads();

    #pragma unroll
    for (int j = 0; j < 4; ++j) {
        const int n = tid + j * 256;
        float acc = bo[n];
        const size_t wrow = (size_t)n * HID;     // Wo[o=n, k]
        for (int kk = 0; kk < HID; ++kk) acc += xs[kk] * Wo[wrow + kk];
        out[row + n] = acc;                      // fp32 store
    }
}

extern "C" void kernel_launch(void* const* d_in, const int* in_sizes, int n_in,
                              void* d_out, int out_size, void* d_ws, size_t ws_size,
                              hipStream_t stream)
{
    const float* hs    = (const float*)d_in[0];
    const float* mask  = (const float*)d_in[1];
    const float* Wq    = (const float*)d_in[2];
    const float* bq    = (const float*)d_in[3];
    const float* Wk    = (const float*)d_in[4];
    const float* bk    = (const float*)d_in[5];
    const float* Wv    = (const float*)d_in[6];
    const float* bv    = (const float*)d_in[7];
    const float* Wo    = (const float*)d_in[8];
    const float* bo    = (const float*)d_in[9];
    // d_in[10] = beta: cancels exactly inside the ConsMax max-shift.
    const float* gamma = (const float*)d_in[11];
    float* out = (float*)d_out;

    // ws: 3 per-head bf16 slices [S,HD] (768 KB) + bf16 ctx [B,S,HID] (8.4 MB)
    u16* qs  = (u16*)d_ws;
    u16* ks  = qs + (size_t)S_ * HD;
    u16* vs  = ks + (size_t)S_ * HD;
    u16* ctx = vs + (size_t)S_ * HD;

    for (int bh = 0; bh < B_ * NH; ++bh) {
        const int b = bh >> 4, h = bh & (NH - 1);
        qkv_head<<<dim3(S_, 3), 64, 0, stream>>>(hs, Wq, bq, Wk, bk, Wv, bv,
                                                 qs, ks, vs, b, h);
        attn_head<<<dim3(S_ / 4), 256, 0, stream>>>(qs, ks, vs, mask, gamma,
                                                    ctx, b, h);
    }
    out_proj<<<dim3(M_), 256, 0, stream>>>(ctx, Wo, bo, out);
}

// Round 8
// 317.788 us; speedup vs baseline: 37.1618x; 37.1618x over previous
//
#include <hip/hip_runtime.h>

// ConsMaxAttention MI355X — ROUND 8: MFMA everywhere.
// r7 anchored correctness (naive, 11.8 ms). This round: bf16 MFMA GEMMs
// (16x16x32) + flash ConsMax attention. Verified layouts (guide §3):
//   A-frag: A[m=lane&15][k=(lane>>4)*8+j]   B-frag: B[k=(lane>>4)*8+j][n=lane&15]
//   C/D:    col=lane&15, row=(lane>>4)*4+reg
// ws (29.4 MB <= 32 MB proven safe in r3): q|k|v [B,NH,S,HD] bf16 + ctx0;
// ctx1 aliases q's dead batch-0 half via attn(b0) -> attn(b1) launch order.

typedef unsigned short u16;
typedef __attribute__((ext_vector_type(8))) short short8;
typedef __attribute__((ext_vector_type(4))) float floatx4;

constexpr int B_  = 2;
constexpr int S_  = 2048;
constexpr int HID = 1024;
constexpr int NH  = 16;
constexpr int HD  = 64;
constexpr int M_  = B_ * S_;   // 4096

__device__ __forceinline__ float us2f(u16 u) {
    union { unsigned int i; float f; } x;
    x.i = ((unsigned int)u) << 16;
    return x.f;
}
__device__ __forceinline__ u16 f2us(float f) {
    union { float f; unsigned int i; } x;
    x.f = f;
    unsigned int r = x.i + 0x7FFFu + ((x.i >> 16) & 1u);  // RNE
    return (u16)(r >> 16);
}

// ---------------------------------------------------------------------------
// QKV GEMM: C[m, n] = hs[m,:]·W[n,:] + b[n], N spans 3 projections (3072).
// 128x128 tile, BK=32, fragment-order LDS, bf16 head-split stores.
__global__ __launch_bounds__(256)
void qkv_gemm(const float* __restrict__ hs,
              const float* __restrict__ Wq, const float* __restrict__ bq,
              const float* __restrict__ Wk, const float* __restrict__ bk,
              const float* __restrict__ Wv, const float* __restrict__ bv,
              u16* __restrict__ Qo, u16* __restrict__ Ko, u16* __restrict__ Vo)
{
    __shared__ u16 Alds[4096];   // 128x32 in A-fragment order (8 subtiles x 1KB)
    __shared__ u16 Blds[4096];

    const int tid = threadIdx.x;
    const int m0  = blockIdx.x * 128;
    const int n0g = blockIdx.y * 128;           // [0, 3072)
    const int p   = n0g >> 10;                  // projection 0/1/2
    const float* W  = (p == 0) ? Wq : (p == 1) ? Wk : Wv;
    const float* bi = (p == 0) ? bq : (p == 1) ? bk : bv;
    u16*        Out = (p == 0) ? Qo : (p == 1) ? Ko : Vo;
    const int n0 = n0g & 1023;                  // col base within projection

    const int w = tid >> 6, l = tid & 63;
    const int wy = w >> 1, wx = w & 1;
    const int r  = tid >> 1;                    // staging row 0..127
    const int hh = tid & 1;                     // staging k-half

    floatx4 acc[4][4];
    #pragma unroll
    for (int i = 0; i < 4; ++i)
        #pragma unroll
        for (int j = 0; j < 4; ++j) acc[i][j] = (floatx4){0.f, 0.f, 0.f, 0.f};

    for (int k0 = 0; k0 < HID; k0 += 32) {
        const float* Ap = hs + (size_t)(m0 + r) * HID + k0 + 16 * hh;
        const float* Bp = W  + (size_t)(n0 + r) * HID + k0 + 16 * hh;
        float af[16], bf[16];
        #pragma unroll
        for (int c = 0; c < 4; ++c) {
            float4 t = *(const float4*)(Ap + 4 * c);
            af[4*c] = t.x; af[4*c+1] = t.y; af[4*c+2] = t.z; af[4*c+3] = t.w;
            float4 u = *(const float4*)(Bp + 4 * c);
            bf[4*c] = u.x; bf[4*c+1] = u.y; bf[4*c+2] = u.z; bf[4*c+3] = u.w;
        }
        __syncthreads();                        // prev compute done reading LDS
        #pragma unroll
        for (int c2 = 0; c2 < 2; ++c2) {        // two 8-elem chunks
            const int quad  = 2 * hh + c2;
            const int lane8 = (r & 15) + 16 * quad;
            u16 ta[8], tb[8];
            #pragma unroll
            for (int j = 0; j < 8; ++j) { ta[j] = f2us(af[8*c2+j]); tb[j] = f2us(bf[8*c2+j]); }
            *(short8*)&Alds[(r >> 4) * 512 + lane8 * 8] = *(short8*)ta;
            *(short8*)&Blds[(r >> 4) * 512 + lane8 * 8] = *(short8*)tb;
        }
        __syncthreads();

        short8 afr[4], bfr[4];
        #pragma unroll
        for (int i = 0; i < 4; ++i) afr[i] = *(const short8*)&Alds[(wy*4 + i) * 512 + l * 8];
        #pragma unroll
        for (int j = 0; j < 4; ++j) bfr[j] = *(const short8*)&Blds[(wx*4 + j) * 512 + l * 8];
        #pragma unroll
        for (int i = 0; i < 4; ++i)
            #pragma unroll
            for (int j = 0; j < 4; ++j)
                acc[i][j] = __builtin_amdgcn_mfma_f32_16x16x32_bf16(afr[i], bfr[j], acc[i][j], 0, 0, 0);
    }

    #pragma unroll
    for (int i = 0; i < 4; ++i)
        #pragma unroll
        for (int j = 0; j < 4; ++j) {
            const int nn   = n0 + wx * 64 + j * 16 + (l & 15);
            const int head = nn >> 6, dd = nn & 63;
            const float bb_ = bi[nn];
            #pragma unroll
            for (int rg = 0; rg < 4; ++rg) {
                const int mm = m0 + wy * 64 + i * 16 + (l >> 4) * 4 + rg;
                const int b  = mm >> 11, ss = mm & (S_ - 1);
                Out[(((size_t)b * NH + head) * S_ + ss) * HD + dd] =
                    f2us(acc[i][j][rg] + bb_);
            }
        }
}

// ---------------------------------------------------------------------------
// Flash ConsMax attention (one batch per launch). 64 q-rows/block, 4 waves;
// Q-frags in registers; K row-major [64][72]; V transposed [d][key];
// P via wave-private LDS in A-frag order. ctx: per-batch [S, HID] bf16.
__global__ __launch_bounds__(256)
void attn_mfma(const u16* __restrict__ Qg, const u16* __restrict__ Kg,
               const u16* __restrict__ Vg, const float* __restrict__ mask,
               const float* __restrict__ gamma, u16* __restrict__ ctx, int b0)
{
    __shared__ u16 Klds[64][72];
    __shared__ u16 Vt[64][72];        // Vt[d][key]
    __shared__ u16 Plds[4][1024];     // per-wave: [2 ksteps][64 lanes][8]
    __shared__ float maskadd[64];

    const int tid = threadIdx.x;
    const int w = tid >> 6, l = tid & 63;
    const int quad = l >> 4, l16 = l & 15;
    const int qb = blockIdx.x;
    const int h  = blockIdx.y;
    const int bh = b0 * NH + h;

    const u16* Qb = Qg + (size_t)bh * S_ * HD;
    const u16* Kb = Kg + (size_t)bh * S_ * HD;
    const u16* Vb = Vg + (size_t)bh * S_ * HD;

    short8 qf[2];                     // Q A-frags: rows qb*64+16w+l16, k=d
    #pragma unroll
    for (int t = 0; t < 2; ++t)
        qf[t] = *(const short8*)(Qb + ((size_t)qb * 64 + 16 * w + l16) * HD + 32 * t + quad * 8);

    floatx4 o_acc[4];
    #pragma unroll
    for (int j = 0; j < 4; ++j) o_acc[j] = (floatx4){0.f, 0.f, 0.f, 0.f};
    float m_run[4] = {-1e30f, -1e30f, -1e30f, -1e30f};

    const int r = tid >> 2;           // staging key row
    const int c = (tid & 3) * 16;     // staging d-chunk

    for (int kt = 0; kt < S_ / 64; ++kt) {
        const u16* Kp = Kb + ((size_t)kt * 64 + r) * HD + c;
        const u16* Vp = Vb + ((size_t)kt * 64 + r) * HD + c;
        uint4 k0v = *(const uint4*)Kp, k1v = *(const uint4*)(Kp + 8);
        uint4 v0v = *(const uint4*)Vp, v1v = *(const uint4*)(Vp + 8);
        float ma = 0.0f;
        if (tid < 64) ma = (1.0f - mask[(size_t)b0 * S_ + kt * 64 + tid]) * -10000.0f;
        __syncthreads();              // all waves done with prev K/V tiles
        *(short8*)&Klds[r][c]     = *(const short8*)&k0v;
        *(short8*)&Klds[r][c + 8] = *(const short8*)&k1v;
        {
            const u16* ve = (const u16*)&v0v;
            #pragma unroll
            for (int e = 0; e < 8; ++e) Vt[c + e][r] = ve[e];
            const u16* v2 = (const u16*)&v1v;
            #pragma unroll
            for (int e = 0; e < 8; ++e) Vt[c + 8 + e][r] = v2[e];
        }
        if (tid < 64) maskadd[tid] = ma;
        __syncthreads();

        // S = Q·K^T : 16 q-rows x 64 keys per wave
        floatx4 sacc[4];
        #pragma unroll
        for (int j = 0; j < 4; ++j) sacc[j] = (floatx4){0.f, 0.f, 0.f, 0.f};
        #pragma unroll
        for (int t = 0; t < 2; ++t)
            #pragma unroll
            for (int j = 0; j < 4; ++j) {
                short8 kf = *(const short8*)&Klds[j * 16 + l16][32 * t + quad * 8];
                sacc[j] = __builtin_amdgcn_mfma_f32_16x16x32_bf16(qf[t], kf, sacc[j], 0, 0, 0);
            }

        // scale + mask + per-row max (rows quad*4+i, cols j*16+l16)
        float sv[4][4], mt[4];
        #pragma unroll
        for (int i = 0; i < 4; ++i) mt[i] = -1e30f;
        #pragma unroll
        for (int j = 0; j < 4; ++j) {
            const float madd = maskadd[j * 16 + l16];
            #pragma unroll
            for (int i = 0; i < 4; ++i) {
                const float s = sacc[j][i] * 0.125f + madd;
                sv[j][i] = s;
                mt[i] = fmaxf(mt[i], s);
            }
        }
        #pragma unroll
        for (int off = 1; off < 16; off <<= 1)
            #pragma unroll
            for (int i = 0; i < 4; ++i)
                mt[i] = fmaxf(mt[i], __shfl_xor(mt[i], off, 64));

        #pragma unroll
        for (int i = 0; i < 4; ++i) {
            const float nm = fmaxf(m_run[i], mt[i]);
            const float sc = __expf(m_run[i] - nm);
            m_run[i] = nm;
            #pragma unroll
            for (int j = 0; j < 4; ++j) o_acc[j][i] *= sc;
        }

        // P = exp(s - m) -> wave-private LDS in A-frag order (no barrier)
        #pragma unroll
        for (int j = 0; j < 4; ++j) {
            const int col = j * 16 + l16;
            const int ts  = col >> 5;
            const int lp  = 16 * ((col & 31) >> 3);
            const int jb  = col & 7;
            #pragma unroll
            for (int i = 0; i < 4; ++i) {
                const int row = quad * 4 + i;
                Plds[w][ts * 512 + (row + lp) * 8 + jb] = f2us(__expf(sv[j][i] - m_run[i]));
            }
        }

        // O += P·V
        #pragma unroll
        for (int t = 0; t < 2; ++t) {
            short8 pf = *(const short8*)&Plds[w][t * 512 + l * 8];
            #pragma unroll
            for (int j = 0; j < 4; ++j) {
                short8 vf = *(const short8*)&Vt[j * 16 + l16][32 * t + quad * 8];
                o_acc[j] = __builtin_amdgcn_mfma_f32_16x16x32_bf16(pf, vf, o_acc[j], 0, 0, 0);
            }
        }
    }

    const float ig = 1.0f / gamma[0];
    #pragma unroll
    for (int j = 0; j < 4; ++j) {
        const int dd = j * 16 + l16;
        #pragma unroll
        for (int i = 0; i < 4; ++i) {
            const int row = qb * 64 + 16 * w + quad * 4 + i;   // [0, S_)
            ctx[(size_t)row * HID + h * HD + dd] = f2us(o_acc[j][i] * ig);
        }
    }
}

// ---------------------------------------------------------------------------
// Output GEMM: out[m,n] = ctx[m,:]·Wo[n,:] + bo[n], fp32 stores.
__global__ __launch_bounds__(256)
void out_gemm(const u16* __restrict__ ctx0, const u16* __restrict__ ctx1,
              const float* __restrict__ Wo, const float* __restrict__ bo,
              float* __restrict__ out)
{
    __shared__ u16 Alds[4096];
    __shared__ u16 Blds[4096];

    const int tid = threadIdx.x;
    const int m0 = blockIdx.x * 128;
    const int n0 = blockIdx.y * 128;
    const u16* ctx = (m0 < S_) ? ctx0 : ctx1;
    const int mr0 = m0 & (S_ - 1);

    const int w = tid >> 6, l = tid & 63;
    const int wy = w >> 1, wx = w & 1;
    const int r  = tid >> 1;
    const int hh = tid & 1;

    floatx4 acc[4][4];
    #pragma unroll
    for (int i = 0; i < 4; ++i)
        #pragma unroll
        for (int j = 0; j < 4; ++j) acc[i][j] = (floatx4){0.f, 0.f, 0.f, 0.f};

    for (int k0 = 0; k0 < HID; k0 += 32) {
        const u16*   Ap = ctx + (size_t)(mr0 + r) * HID + k0 + 16 * hh;
        const float* Bp = Wo  + (size_t)(n0 + r) * HID + k0 + 16 * hh;
        uint4 a0 = *(const uint4*)Ap, a1 = *(const uint4*)(Ap + 8);
        float bf[16];
        #pragma unroll
        for (int c = 0; c < 4; ++c) {
            float4 u = *(const float4*)(Bp + 4 * c);
            bf[4*c] = u.x; bf[4*c+1] = u.y; bf[4*c+2] = u.z; bf[4*c+3] = u.w;
        }
        __syncthreads();
        {
            const int lane8a = (r & 15) + 16 * (2 * hh);
            const int lane8b = (r & 15) + 16 * (2 * hh + 1);
            *(short8*)&Alds[(r >> 4) * 512 + lane8a * 8] = *(const short8*)&a0;
            *(short8*)&Alds[(r >> 4) * 512 + lane8b * 8] = *(const short8*)&a1;
            u16 tb[8];
            #pragma unroll
            for (int j = 0; j < 8; ++j) tb[j] = f2us(bf[j]);
            *(short8*)&Blds[(r >> 4) * 512 + lane8a * 8] = *(short8*)tb;
            #pragma unroll
            for (int j = 0; j < 8; ++j) tb[j] = f2us(bf[8 + j]);
            *(short8*)&Blds[(r >> 4) * 512 + lane8b * 8] = *(short8*)tb;
        }
        __syncthreads();

        short8 afr[4], bfr[4];
        #pragma unroll
        for (int i = 0; i < 4; ++i) afr[i] = *(const short8*)&Alds[(wy*4 + i) * 512 + l * 8];
        #pragma unroll
        for (int j = 0; j < 4; ++j) bfr[j] = *(const short8*)&Blds[(wx*4 + j) * 512 + l * 8];
        #pragma unroll
        for (int i = 0; i < 4; ++i)
            #pragma unroll
            for (int j = 0; j < 4; ++j)
                acc[i][j] = __builtin_amdgcn_mfma_f32_16x16x32_bf16(afr[i], bfr[j], acc[i][j], 0, 0, 0);
    }

    #pragma unroll
    for (int i = 0; i < 4; ++i)
        #pragma unroll
        for (int j = 0; j < 4; ++j) {
            const int nn = n0 + wx * 64 + j * 16 + (l & 15);
            const float bb_ = bo[nn];
            #pragma unroll
            for (int rg = 0; rg < 4; ++rg) {
                const int mm = m0 + wy * 64 + i * 16 + (l >> 4) * 4 + rg;
                out[(size_t)mm * HID + nn] = acc[i][j][rg] + bb_;
            }
        }
}

extern "C" void kernel_launch(void* const* d_in, const int* in_sizes, int n_in,
                              void* d_out, int out_size, void* d_ws, size_t ws_size,
                              hipStream_t stream)
{
    const float* hs    = (const float*)d_in[0];
    const float* mask  = (const float*)d_in[1];
    const float* Wq    = (const float*)d_in[2];
    const float* bq    = (const float*)d_in[3];
    const float* Wk    = (const float*)d_in[4];
    const float* bk    = (const float*)d_in[5];
    const float* Wv    = (const float*)d_in[6];
    const float* bv    = (const float*)d_in[7];
    const float* Wo    = (const float*)d_in[8];
    const float* bo    = (const float*)d_in[9];
    // d_in[10] = beta: cancels in the ConsMax max-shift.
    const float* gamma = (const float*)d_in[11];
    float* out = (float*)d_out;

    const size_t tsz = (size_t)B_ * NH * S_ * HD;   // 4,194,304
    u16* q    = (u16*)d_ws;
    u16* k    = q + tsz;
    u16* v    = k + tsz;
    u16* ctx0 = v + tsz;          // batch-0 ctx [S, HID]
    u16* ctx1 = q;                // aliases q's batch-0 half (dead after attn b0)

    qkv_gemm<<<dim3(32, 24), 256, 0, stream>>>(hs, Wq, bq, Wk, bk, Wv, bv, q, k, v);
    attn_mfma<<<dim3(32, 16), 256, 0, stream>>>(q, k, v, mask, gamma, ctx0, 0);
    attn_mfma<<<dim3(32, 16), 256, 0, stream>>>(q, k, v, mask, gamma, ctx1, 1);
    out_gemm<<<dim3(32, 8), 256, 0, stream>>>(ctx0, ctx1, Wo, bo, out);
}